// Round 1
// baseline (2625.660 us; speedup 1.0000x reference)
//
#include <hip/hip_runtime.h>
#include <stdint.h>

#define Bc 8
#define Cc 64
#define Hc 256
#define Wc 256
#define Vc (Hc*Wc)            // 65536
#define REc ((Hc-1)*Wc)       // 65280 row edges
#define Ec (REc + Hc*(Wc-1))  // 130560 total edges
#define VM1 (Vc-1)            // 65535

__device__ __forceinline__ void edge_uv(int e, int& u, int& v){
  if (e < REc){ u = e; v = e + Wc; }                       // row edge: (i,j)-(i+1,j)
  else { int k = e - REc; int i = k / (Wc-1); int j = k - i*(Wc-1); u = i*Wc + j; v = u + 1; }
}

__global__ void k_init(int* __restrict__ L, int* __restrict__ outp){
  int t = blockIdx.x*blockDim.x + threadIdx.x;
  if (t < Bc*Vc) L[t] = t & (Vc-1);
  if (t < Bc*VM1){ outp[2*t] = 0; outp[2*t+1] = Wc; }      // ref fill: index[0] = (0, 256)
}

__global__ void k_weights(const float* __restrict__ g, float* __restrict__ wgt,
                          unsigned char* __restrict__ sel, int* __restrict__ elist){
  int t = blockIdx.x*blockDim.x + threadIdx.x;
  if (t >= Bc*Ec) return;
  int b = t / Ec; int e = t - b*Ec;
  int u, v; edge_uv(e, u, v);
  const float* p = g + (size_t)b*Cc*Vc;
  float s = 0.f;
  #pragma unroll 8
  for (int c = 0; c < Cc; ++c){                            // sequential c order (match XLA)
    float d = p[(size_t)c*Vc + u] - p[(size_t)c*Vc + v];
    s += d*d;
  }
  wgt[t] = s + 1.0f;
  sel[t] = 0;
  elist[t] = e;
}

__global__ void __launch_bounds__(1024,1)
k_mst(const float* __restrict__ wgt_all,
      int* __restrict__ L_all, int* __restrict__ par_all,
      unsigned long long* __restrict__ best_all,
      unsigned char* __restrict__ sel_all,
      int* __restrict__ elA_all, int* __restrict__ elB_all,
      int* __restrict__ outp){
  const int b = blockIdx.x;
  const int tid = threadIdx.x;
  const int lane = tid & 63, wave = tid >> 6;
  const float* wb = wgt_all + (size_t)b*Ec;
  int* L   = L_all   + (size_t)b*Vc;
  int* par = par_all + (size_t)b*Vc;
  unsigned long long* best = best_all + (size_t)b*Vc;
  unsigned char* sel = sel_all + (size_t)b*Ec;
  int* cur = elA_all + (size_t)b*Ec;
  int* nxt = elB_all + (size_t)b*Ec;
  int m = Ec;

  __shared__ int s_hook, s_chg;
  __shared__ int s_wsum[16];

  for (int round = 0; round < 24; ++round){
    if (tid == 0) s_hook = 0;
    for (int i = tid; i < Vc; i += 1024) best[i] = 0xFFFFFFFFFFFFFFFFull;
    __syncthreads();

    // --- per-component min edge (lexicographic (w_bits, eidx) via packed u64 atomicMin)
    for (int i = tid; i < m; i += 1024){
      int e = cur[i]; int u, v; edge_uv(e, u, v);
      int cu = L[u], cv = L[v];
      if (cu != cv){
        unsigned long long pack = ((unsigned long long)__float_as_uint(wb[e]) << 32) | (unsigned)e;
        atomicMin(&best[cu], pack);
        atomicMin(&best[cv], pack);
      }
    }
    __syncthreads();

    // --- hook (mutual-min pair: smaller id stays root)
    for (int r = tid; r < Vc; r += 1024){
      int pr = r;
      if (L[r] == r){
        unsigned long long p = best[r];
        if (p != 0xFFFFFFFFFFFFFFFFull){
          int e = (int)(unsigned)p; int u, v; edge_uv(e, u, v);
          int cu = L[u], cv = L[v];
          int other = (cu == r) ? cv : cu;
          sel[e] = 1;
          s_hook = 1;
          pr = (best[other] == p && r < other) ? r : other;
        }
      }
      par[r] = pr;
    }
    __syncthreads();
    int hooked = s_hook;
    __syncthreads();
    if (!hooked) break;

    // --- pointer jumping to convergence
    for (int j = 0; j < 17; ++j){
      if (tid == 0) s_chg = 0;
      __syncthreads();
      for (int i = tid; i < Vc; i += 1024){
        int p = par[i]; int gp = par[p];
        if (p != gp){ par[i] = gp; s_chg = 1; }
      }
      __syncthreads();
      int chg = s_chg;
      __syncthreads();
      if (!chg) break;
    }

    // --- relabel
    for (int i = tid; i < Vc; i += 1024) L[i] = par[L[i]];
    __syncthreads();

    // --- compact active edges (keeps ascending order, ping-pong lists)
    int chunk = (m + 1023) >> 10;
    int lo = tid*chunk; int hi = min(m, lo + chunk);
    int cnt = 0;
    for (int i = lo; i < hi; ++i){
      int e = cur[i]; int u, v; edge_uv(e, u, v);
      if (L[u] != L[v]) ++cnt;
    }
    int x = cnt;
    #pragma unroll
    for (int off = 1; off < 64; off <<= 1){ int y = __shfl_up(x, off, 64); if (lane >= off) x += y; }
    if (lane == 63) s_wsum[wave] = x;
    __syncthreads();
    if (wave == 0){
      int ts = (lane < 16) ? s_wsum[lane] : 0;
      #pragma unroll
      for (int off = 1; off < 16; off <<= 1){ int y = __shfl_up(ts, off, 64); if (lane >= off) ts += y; }
      if (lane < 16) s_wsum[lane] = ts;
    }
    __syncthreads();
    int base = (wave == 0 ? 0 : s_wsum[wave-1]) + x - cnt;
    int total = s_wsum[15];
    for (int i = lo; i < hi; ++i){
      int e = cur[i]; int u, v; edge_uv(e, u, v);
      if (L[u] != L[v]) nxt[base++] = e;
    }
    __syncthreads();
    int* tmp = cur; cur = nxt; nxt = tmp; m = total;
  }

  // --- output compaction: selected edges in ascending e order
  {
    const int chunk = (Ec + 1023) >> 10; // 128
    int lo = tid*chunk; int hi = min(Ec, lo + chunk);
    int cnt = 0;
    for (int i = lo; i < hi; ++i) cnt += sel[i];
    int x = cnt;
    #pragma unroll
    for (int off = 1; off < 64; off <<= 1){ int y = __shfl_up(x, off, 64); if (lane >= off) x += y; }
    if (lane == 63) s_wsum[wave] = x;
    __syncthreads();
    if (wave == 0){
      int ts = (lane < 16) ? s_wsum[lane] : 0;
      #pragma unroll
      for (int off = 1; off < 16; off <<= 1){ int y = __shfl_up(ts, off, 64); if (lane >= off) ts += y; }
      if (lane < 16) s_wsum[lane] = ts;
    }
    __syncthreads();
    int pos = (wave == 0 ? 0 : s_wsum[wave-1]) + x - cnt;
    int* ob = outp + (size_t)b*VM1*2;
    for (int i = lo; i < hi; ++i){
      if (sel[i]){ int u, v; edge_uv(i, u, v); ob[2*pos] = u; ob[2*pos+1] = v; ++pos; }
    }
  }
}

extern "C" void kernel_launch(void* const* d_in, const int* in_sizes, int n_in,
                              void* d_out, int out_size, void* d_ws, size_t ws_size,
                              hipStream_t stream) {
  const float* g = (const float*)d_in[0];
  int* outp = (int*)d_out;

  char* ws = (char*)d_ws;
  size_t off = 0;
  auto alloc = [&](size_t bytes) -> void* {
    void* p = ws + off; off += (bytes + 511) & ~(size_t)511; return p;
  };
  unsigned long long* best = (unsigned long long*)alloc((size_t)Bc*Vc*8);
  float* wgt = (float*)alloc((size_t)Bc*Ec*4);
  int* L     = (int*)alloc((size_t)Bc*Vc*4);
  int* par   = (int*)alloc((size_t)Bc*Vc*4);
  unsigned char* sel = (unsigned char*)alloc((size_t)Bc*Ec);
  int* elA   = (int*)alloc((size_t)Bc*Ec*4);
  int* elB   = (int*)alloc((size_t)Bc*Ec*4);

  k_init<<<(Bc*Vc + 255)/256, 256, 0, stream>>>(L, outp);
  k_weights<<<(Bc*Ec + 255)/256, 256, 0, stream>>>(g, wgt, sel, elA);
  k_mst<<<Bc, 1024, 0, stream>>>(wgt, L, par, best, sel, elA, elB, outp);
}

// Round 2
// 443.455 us; speedup vs baseline: 5.9209x; 5.9209x over previous
//
#include <hip/hip_runtime.h>
#include <stdint.h>

#define Bc 8
#define Cc 64
#define Hc 256
#define Wc 256
#define Vc (Hc*Wc)            // 65536
#define REc ((Hc-1)*Wc)       // 65280 row edges
#define Ec (REc + Hc*(Wc-1))  // 130560 total edges
#define VM1 (Vc-1)            // 65535
#define NR 16
#define INF64 0xFFFFFFFFFFFFFFFFull

__device__ __forceinline__ void edge_uv(int e, int& u, int& v){
  if (e < REc){ u = e; v = e + Wc; }                       // row edge: (i,j)-(i+1,j)
  else { int k = e - REc; int i = k / (Wc-1); int j = k - i*(Wc-1); u = i*Wc + j; v = u + 1; }
}

__global__ void k_init(int* __restrict__ L, unsigned long long* __restrict__ best,
                       unsigned char* __restrict__ sel, int* __restrict__ act,
                       int* __restrict__ outp){
  int t = blockIdx.x*blockDim.x + threadIdx.x;
  if (t < Bc*Vc){ L[t] = t & VM1; best[t] = INF64; }
  if (t < Bc*Ec) sel[t] = 0;
  if (t < Bc*VM1){ outp[2*t] = 0; outp[2*t+1] = Wc; }      // ref fill value
  if (t < (NR+2)*Bc) act[t] = (t < Bc) ? 1 : 0;            // act[0][*]=1
}

// packed (weight_bits<<32 | edge_idx): lexicographic (w, e) min == u64 min
__global__ void k_weights(const float* __restrict__ g, unsigned long long* __restrict__ wp){
  int t = blockIdx.x*blockDim.x + threadIdx.x;
  if (t >= Bc*Ec) return;
  int b = t / Ec; int e = t - b*Ec;
  int u, v; edge_uv(e, u, v);
  const float* p = g + (size_t)b*Cc*Vc;
  float s = 0.f;
  #pragma unroll 8
  for (int c = 0; c < Cc; ++c){                            // sequential c order (bit-exact vs ref)
    float d = p[(size_t)c*Vc + u] - p[(size_t)c*Vc + v];
    s += d*d;
  }
  s += 1.0f;
  wp[t] = ((unsigned long long)__float_as_uint(s) << 32) | (unsigned)e;
}

// vertex-centric: min over active incident edges -> atomicMin(best[comp])
__global__ void __launch_bounds__(256)
k_scan(const int* __restrict__ L, const unsigned long long* __restrict__ wp,
       unsigned long long* __restrict__ best, const int* __restrict__ act, int r){
  int t = blockIdx.x*blockDim.x + threadIdx.x;             // [0, B*V)
  int b = t >> 16;
  if (!act[r*Bc + b]) return;
  int v = t & VM1;
  int i = v >> 8, j = v & (Wc-1);
  const int base = b << 16;
  const size_t ebase = (size_t)b*Ec;
  int c = L[t];
  unsigned long long m = INF64;
  if (i > 0     && L[base + v - Wc] != c){ unsigned long long x = wp[ebase + v - Wc];                  if (x < m) m = x; }
  if (i < Hc-1  && L[base + v + Wc] != c){ unsigned long long x = wp[ebase + v];                       if (x < m) m = x; }
  if (j > 0     && L[base + v - 1 ] != c){ unsigned long long x = wp[ebase + REc + i*(Wc-1) + j - 1];  if (x < m) m = x; }
  if (j < Wc-1  && L[base + v + 1 ] != c){ unsigned long long x = wp[ebase + REc + i*(Wc-1) + j    ];  if (x < m) m = x; }
  if (m != INF64) atomicMin(&best[base + c], m);
}

// roots: select best edge, mutual-pair break (smaller id stays root)
__global__ void __launch_bounds__(256)
k_hook(const int* __restrict__ L, const unsigned long long* __restrict__ best,
       int* __restrict__ par, unsigned char* __restrict__ sel, int* __restrict__ act, int r){
  int t = blockIdx.x*blockDim.x + threadIdx.x;
  int b = t >> 16;
  if (!act[r*Bc + b]) return;
  int v = t & VM1;
  if (L[t] != v) return;                                   // roots only (invariant: L[L[t]]==L[t])
  const int base = b << 16;
  unsigned long long p = best[t];
  int pr = v;
  if (p != INF64){
    int e = (int)(unsigned)p; int eu, ev; edge_uv(e, eu, ev);
    int cu = L[base + eu], cv = L[base + ev];
    int other = (cu == v) ? cv : cu;
    sel[(size_t)b*Ec + e] = 1;
    act[(r+1)*Bc + b] = 1;                                 // racy same-value store: fine
    pr = (best[base + other] == p && v < other) ? v : other;
  }
  par[t] = pr;
}

// relabel: chase hook-forest to root (par is read-only here -> race-free), reset best
__global__ void __launch_bounds__(256)
k_merge(int* __restrict__ L, const int* __restrict__ par,
        unsigned long long* __restrict__ best, const int* __restrict__ act, int r){
  int t = blockIdx.x*blockDim.x + threadIdx.x;
  int b = t >> 16;
  if (!act[r*Bc + b]) return;
  const int base = b << 16;
  int rt = L[t];
  int p = par[base + rt];
  while (p != rt){ rt = p; p = par[base + rt]; }
  L[t] = rt;
  best[t] = INF64;
}

// per-batch ordered compaction of selected edges -> output (u,v) pairs
__global__ void __launch_bounds__(1024,1)
k_out(const unsigned char* __restrict__ sel_all, int* __restrict__ outp){
  const int b = blockIdx.x;
  const int tid = threadIdx.x;
  const int lane = tid & 63, wave = tid >> 6;
  const unsigned char* sel = sel_all + (size_t)b*Ec;
  __shared__ int s_wsum[16];
  const int chunk = (Ec + 1023) >> 10;                     // 128
  int lo = tid*chunk; int hi = min(Ec, lo + chunk);
  int cnt = 0;
  for (int i = lo; i < hi; ++i) cnt += sel[i];
  int x = cnt;
  #pragma unroll
  for (int off = 1; off < 64; off <<= 1){ int y = __shfl_up(x, off, 64); if (lane >= off) x += y; }
  if (lane == 63) s_wsum[wave] = x;
  __syncthreads();
  if (wave == 0){
    int ts = (lane < 16) ? s_wsum[lane] : 0;
    #pragma unroll
    for (int off = 1; off < 16; off <<= 1){ int y = __shfl_up(ts, off, 64); if (lane >= off) ts += y; }
    if (lane < 16) s_wsum[lane] = ts;
  }
  __syncthreads();
  int pos = (wave == 0 ? 0 : s_wsum[wave-1]) + x - cnt;
  int* ob = outp + (size_t)b*VM1*2;
  for (int i = lo; i < hi; ++i){
    if (sel[i]){ int u, v; edge_uv(i, u, v); ob[2*pos] = u; ob[2*pos+1] = v; ++pos; }
  }
}

extern "C" void kernel_launch(void* const* d_in, const int* in_sizes, int n_in,
                              void* d_out, int out_size, void* d_ws, size_t ws_size,
                              hipStream_t stream) {
  const float* g = (const float*)d_in[0];
  int* outp = (int*)d_out;

  char* ws = (char*)d_ws;
  size_t off = 0;
  auto alloc = [&](size_t bytes) -> void* {
    void* p = ws + off; off += (bytes + 511) & ~(size_t)511; return p;
  };
  unsigned long long* best = (unsigned long long*)alloc((size_t)Bc*Vc*8);
  unsigned long long* wp   = (unsigned long long*)alloc((size_t)Bc*Ec*8);
  int* L   = (int*)alloc((size_t)Bc*Vc*4);
  int* par = (int*)alloc((size_t)Bc*Vc*4);
  unsigned char* sel = (unsigned char*)alloc((size_t)Bc*Ec);
  int* act = (int*)alloc((size_t)(NR+2)*Bc*4);

  k_init<<<(Bc*Ec + 255)/256, 256, 0, stream>>>(L, best, sel, act, outp);
  k_weights<<<(Bc*Ec + 255)/256, 256, 0, stream>>>(g, wp);
  for (int r = 0; r < NR; ++r){
    k_scan <<<(Bc*Vc + 255)/256, 256, 0, stream>>>(L, wp, best, act, r);
    k_hook <<<(Bc*Vc + 255)/256, 256, 0, stream>>>(L, best, par, sel, act, r);
    k_merge<<<(Bc*Vc + 255)/256, 256, 0, stream>>>(L, par, best, act, r);
  }
  k_out<<<Bc, 1024, 0, stream>>>(sel, outp);
}